// Round 13
// baseline (2186.089 us; speedup 1.0000x reference)
//
#include <hip/hip_runtime.h>
#include <math.h>

// Problem constants
#define Bq 8
#define Tt 128
#define Ee 384
#define Hh 768
#define Ll 9
#define GATE 1536   // 4*E

__device__ __forceinline__ float fast_sigmoid(float x) {
    return 1.f / (1.f + __expf(-x));
}
__device__ __forceinline__ float fast_tanh(float x) {
    return 1.f - 2.f / (__expf(2.f * x) + 1.f);
}

// ---------------------------------------------------------------------------
// Generic f32 GEMM, 64x64 tiles (unchanged from R12, known-good).
// ---------------------------------------------------------------------------
#define BM 64
#define BN 64
#define BKk 16

__global__ __launch_bounds__(256) void k_gemm(
    const float* __restrict__ A, const float* __restrict__ Bw, float* __restrict__ C,
    int M, int N, int K,
    long sAz, long sBz, long sCz,
    const float* __restrict__ b1, const float* __restrict__ b2, long sbz,
    const float* __restrict__ bbn)
{
    int z = blockIdx.z;
    A += (long)z * sAz;
    Bw += (long)z * sBz;
    C += (long)z * sCz;
    const float* bb1 = b1 ? b1 + (long)z * sbz : nullptr;
    const float* bb2 = b2 ? b2 + (long)z * sbz : nullptr;

    int n0 = blockIdx.x * BN;
    int m0 = blockIdx.y * BM;
    int tid = threadIdx.x;

    __shared__ float As[BKk][BM];
    __shared__ float Bs[BKk][BN];

    int lr = tid & 63;          // row within tile
    int lc = (tid >> 6) * 4;    // col group 0,4,8,12
    int tx = tid & 15;          // microtile col
    int ty = tid >> 4;          // microtile row

    float acc[4][4];
#pragma unroll
    for (int i = 0; i < 4; ++i)
#pragma unroll
        for (int j = 0; j < 4; ++j) acc[i][j] = 0.f;

    for (int k0 = 0; k0 < K; k0 += BKk) {
        float4 a0 = *(const float4*)&A[(long)(m0 + lr) * K + k0 + lc];
        float4 w0 = *(const float4*)&Bw[(long)(n0 + lr) * K + k0 + lc];
        __syncthreads();
        As[lc + 0][lr] = a0.x; As[lc + 1][lr] = a0.y; As[lc + 2][lr] = a0.z; As[lc + 3][lr] = a0.w;
        Bs[lc + 0][lr] = w0.x; Bs[lc + 1][lr] = w0.y; Bs[lc + 2][lr] = w0.z; Bs[lc + 3][lr] = w0.w;
        __syncthreads();
#pragma unroll
        for (int kk = 0; kk < BKk; ++kk) {
            float av[4], bv[4];
            *(float4*)&av[0] = *(float4*)&As[kk][ty * 4];
            *(float4*)&bv[0] = *(float4*)&Bs[kk][tx * 4];
#pragma unroll
            for (int i = 0; i < 4; ++i)
#pragma unroll
                for (int j = 0; j < 4; ++j)
                    acc[i][j] = fmaf(av[i], bv[j], acc[i][j]);
        }
    }

#pragma unroll
    for (int i = 0; i < 4; ++i) {
        long m = m0 + ty * 4 + i;
#pragma unroll
        for (int j = 0; j < 4; ++j) {
            int n = n0 + tx * 4 + j;
            float val = acc[i][j];
            if (bb1) val += bb1[n];
            if (bb2) val += bb2[n];
            if (bbn) val += bbn[(m >> 7) * (long)N + n];
            C[m * N + n] = val;
        }
    }
}

// ---------------------------------------------------------------------------
// LSTM recurrence, sentinel-dataflow + sweep polling, FINE 6-row slices:
// 128 blocks (64 slices/dir) halve the per-CU compute phase (288 FMA/thread).
// Thread (kq=tid>>3: 12-k range, rg=tid&7: 3 gate rows), W 36 floats/thread.
// Wave-level shfl_xor reduction collapses each wave's 8 kq-slices in-register
// (lane bits 3..5 = kq&7), so part = [4 waves][8 b][24 rl] = 3.2 KB and the
// update phase reads only 4 partials per gate.
// Yout pre-filled with 0xFFFFFFFF (NaN); h always finite.
// ---------------------------------------------------------------------------
__device__ __forceinline__ bool has_sent(unsigned long long v) {
    return ((unsigned)v == 0xFFFFFFFFu) || ((unsigned)(v >> 32) == 0xFFFFFFFFu);
}

__global__ __launch_bounds__(256, 1) void k_lstm(
    const float* __restrict__ G, const float* __restrict__ Whh, float* Yout)
{
    int bid = blockIdx.x;
    int d = bid >> 6;           // direction
    int s = bid & 63;           // slice: h-rows s*6 .. s*6+5
    int tid = threadIdx.x;
    int kq = tid >> 3;          // 0..31 (k-range of 12)
    int rg = tid & 7;           // 0..7  (3 gate-rows each)
    int kq12 = kq * 12;

    __shared__ float hl[8 * 384];       // h_prev for all batches of this dir
    __shared__ float part[4 * 200];     // [wave q][b(stride 25)][rl 0..23]

    // W slice: 3 gate rows x 12 k = 36 floats (register-resident)
    float W_[3][12];
    const float* Wd = Whh + (long)d * GATE * Ee;
#pragma unroll
    for (int r = 0; r < 3; ++r) {
        int rl = rg * 3 + r;            // 0..23
        int g = rl / 6, rr = rl % 6;
        const float* src = Wd + (long)(g * Ee + s * 6 + rr) * Ee + kq12;
#pragma unroll
        for (int k4 = 0; k4 < 3; ++k4) {
            float4 w = *(const float4*)&src[k4 * 4];
            W_[r][k4 * 4 + 0] = w.x;
            W_[r][k4 * 4 + 1] = w.y;
            W_[r][k4 * 4 + 2] = w.z;
            W_[r][k4 * 4 + 3] = w.w;
        }
    }

    float cst = 0.f;                    // cell state for update thread
    bool upd = tid < 48;
    int ub = upd ? (tid / 6) : 0;       // batch
    int ur = upd ? (tid - ub * 6) : 0;  // h-row within slice

    // G prefetch (one timestep ahead)
    float gpre[4];
    const float* gbase = G + ((long)d * 1024 + ub * Tt) * GATE + s * 6 + ur;
    {
        int tt0 = d ? 127 : 0;
        if (upd) {
#pragma unroll
            for (int g = 0; g < 4; ++g) gpre[g] = gbase[(long)tt0 * GATE + g * Ee];
        }
    }

    float4* hl4 = (float4*)hl;

    for (int it = 0; it < 128; ++it) {
        int tt = d ? (127 - it) : it;
        int tp = d ? (tt + 1) : (tt - 1);

        // stage h_{prev}: parallel-issue all 6 words, sweep-verify
        if (it == 0) {
            float4 z4 = make_float4(0.f, 0.f, 0.f, 0.f);
#pragma unroll
            for (int ii = 0; ii < 3; ++ii) hl4[tid + 256 * ii] = z4;
        } else {
            const unsigned long long* sp[6];
            unsigned long long v[6];
#pragma unroll
            for (int ii = 0; ii < 3; ++ii) {
                int i4 = tid + 256 * ii;       // 0..767
                int b = i4 / 96, k4 = i4 - b * 96;
                const unsigned long long* base = (const unsigned long long*)
                    &Yout[((long)(b * Tt + tp)) * Hh + d * Ee + k4 * 4];
                sp[2 * ii] = base;
                sp[2 * ii + 1] = base + 1;
            }
#pragma unroll
            for (int j = 0; j < 6; ++j)
                v[j] = __hip_atomic_load(sp[j], __ATOMIC_RELAXED, __HIP_MEMORY_SCOPE_AGENT);
            for (;;) {
                bool any = false;
#pragma unroll
                for (int j = 0; j < 6; ++j) {
                    if (has_sent(v[j])) {
                        v[j] = __hip_atomic_load(sp[j], __ATOMIC_RELAXED, __HIP_MEMORY_SCOPE_AGENT);
                        any = true;
                    }
                }
                if (!any) break;
            }
#pragma unroll
            for (int ii = 0; ii < 3; ++ii) {
                int i4 = tid + 256 * ii;
                float2 flo = __builtin_bit_cast(float2, v[2 * ii]);
                float2 fhi = __builtin_bit_cast(float2, v[2 * ii + 1]);
                hl4[i4] = make_float4(flo.x, flo.y, fhi.x, fhi.y);
            }
        }
        __syncthreads();

        float acc[8][3];
#pragma unroll
        for (int b = 0; b < 8; ++b)
#pragma unroll
            for (int r = 0; r < 3; ++r) acc[b][r] = 0.f;

#pragma unroll
        for (int k4 = 0; k4 < 3; ++k4) {
#pragma unroll
            for (int b = 0; b < 8; ++b) {
                float4 hv = *(const float4*)&hl[b * 384 + kq12 + k4 * 4];
#pragma unroll
                for (int r = 0; r < 3; ++r) {
                    acc[b][r] = fmaf(W_[r][k4 * 4 + 0], hv.x, acc[b][r]);
                    acc[b][r] = fmaf(W_[r][k4 * 4 + 1], hv.y, acc[b][r]);
                    acc[b][r] = fmaf(W_[r][k4 * 4 + 2], hv.z, acc[b][r]);
                    acc[b][r] = fmaf(W_[r][k4 * 4 + 3], hv.w, acc[b][r]);
                }
            }
        }

        // wave-level reduction over kq&7 (lane bits 3..5), then 8 lanes/wave
        // write the octet-sum to part.
#pragma unroll
        for (int b = 0; b < 8; ++b)
#pragma unroll
            for (int r = 0; r < 3; ++r) {
                float vv = acc[b][r];
                vv += __shfl_xor(vv, 8);
                vv += __shfl_xor(vv, 16);
                vv += __shfl_xor(vv, 32);
                acc[b][r] = vv;
            }
        if ((kq & 7) == 0) {
            int q = kq >> 3;               // wave id 0..3
#pragma unroll
            for (int b = 0; b < 8; ++b)
#pragma unroll
                for (int r = 0; r < 3; ++r)
                    part[q * 200 + b * 25 + rg * 3 + r] = acc[b][r];
        }
        __syncthreads();

        if (upd) {
            float gt[4];
#pragma unroll
            for (int g = 0; g < 4; ++g) {
                int rl = g * 6 + ur;
                gt[g] = gpre[g]
                      + part[0 * 200 + ub * 25 + rl]
                      + part[1 * 200 + ub * 25 + rl]
                      + part[2 * 200 + ub * 25 + rl]
                      + part[3 * 200 + ub * 25 + rl];
            }
            float ig = fast_sigmoid(gt[0]);
            float fg = fast_sigmoid(gt[1]);
            float gg = fast_tanh(gt[2]);
            float og = fast_sigmoid(gt[3]);
            cst = fg * cst + ig * gg;
            float h = og * fast_tanh(cst);
            // fire-and-forget write-through store to the coherence point
            __hip_atomic_store(&Yout[((long)(ub * Tt + tt)) * Hh + d * Ee + s * 6 + ur],
                               h, __ATOMIC_RELAXED, __HIP_MEMORY_SCOPE_AGENT);
            // prefetch next step's G (overlaps next staging)
            if (it != 127) {
                int ttn = d ? (tt - 1) : (tt + 1);
#pragma unroll
                for (int g = 0; g < 4; ++g) gpre[g] = gbase[(long)ttn * GATE + g * Ee];
            }
        }
    }
}

// ---------------------------------------------------------------------------
// Sentinel pre-fill (one launch for Y0+Y1 contiguous region and hs)
// ---------------------------------------------------------------------------
__global__ void k_fill_sent2(float* __restrict__ a, int na4,
                             float* __restrict__ b, int nb4)
{
    int i = blockIdx.x * 256 + threadIdx.x;
    unsigned u = 0xFFFFFFFFu;
    float f = __builtin_bit_cast(float, u);
    float4 f4 = make_float4(f, f, f, f);
    if (i < na4) ((float4*)a)[i] = f4;
    else {
        int j = i - na4;
        if (j < nb4) ((float4*)b)[j] = f4;
    }
}

// ---------------------------------------------------------------------------
// p_term (unchanged)
// ---------------------------------------------------------------------------
__global__ __launch_bounds__(256) void k_pterm(
    const float* __restrict__ hs, const int* __restrict__ qids,
    const float* __restrict__ Wp, float* __restrict__ pterm)
{
    int b = blockIdx.y;
    int chunk = blockIdx.x;
    int tid = threadIdx.x;
    int qid = qids[b];
    __shared__ float hp[Hh];
    for (int i = tid; i < Hh; i += 256) hp[i] = hs[((long)(b * Tt + qid)) * Hh + i];
    __syncthreads();
    int w = tid >> 6, lane = tid & 63;
#pragma unroll
    for (int r = 0; r < 8; ++r) {
        int n = chunk * 32 + w * 8 + r;
        const float* wrow = &Wp[(long)n * Hh];
        float p = 0.f;
#pragma unroll
        for (int k0 = 0; k0 < 3; ++k0) {
            int k = lane * 4 + k0 * 256;
            float4 wv = *(const float4*)&wrow[k];
            float4 hv = *(const float4*)&hp[k];
            p += wv.x * hv.x + wv.y * hv.y + wv.z * hv.z + wv.w * hv.w;
        }
#pragma unroll
        for (int o = 32; o; o >>= 1) p += __shfl_down(p, o);
        if (lane == 0) pterm[b * Hh + n] = p;
    }
}

// ---------------------------------------------------------------------------
// Fused attention (unchanged)
// ---------------------------------------------------------------------------
__global__ __launch_bounds__(256) void k_attn(
    const float* __restrict__ hs, const float* __restrict__ A1, const float* __restrict__ A2,
    const float* __restrict__ v, const float* __restrict__ Wclf,
    float* __restrict__ a_mat, float* __restrict__ logits)
{
    int b = blockIdx.x >> 7, t = blockIdx.x & 127;
    int tid = threadIdx.x;
    long bt = (long)(b * Tt + t);

    __shared__ float a2r[Hh], vr[Hh], hsr[Hh], crow[Hh];
    __shared__ float sc[128], tmp[256], red2[2];

    for (int i = tid; i < Hh; i += 256) {
        a2r[i] = A2[bt * Hh + i];
        vr[i] = v[i];
        hsr[i] = hs[bt * Hh + i];
    }
    __syncthreads();

    {
        int sid = tid >> 1, half = tid & 1;
        float p = 0.f;
        const float* A1r = &A1[((long)(b * Tt + sid)) * Hh + half * 384];
        const float* a2h = &a2r[half * 384];
        const float* vh = &vr[half * 384];
        for (int k = 0; k < 384; k += 4) {
            float4 z = *(const float4*)&A1r[k];
            p += vh[k + 0] * fast_tanh(z.x + a2h[k + 0]);
            p += vh[k + 1] * fast_tanh(z.y + a2h[k + 1]);
            p += vh[k + 2] * fast_tanh(z.z + a2h[k + 2]);
            p += vh[k + 3] * fast_tanh(z.w + a2h[k + 3]);
        }
        tmp[tid] = p;
    }
    __syncthreads();
    if (tid < 128) sc[tid] = tmp[2 * tid] + tmp[2 * tid + 1];
    __syncthreads();

    if (tid < 64) {
        float m = fmaxf(sc[tid], sc[tid + 64]);
#pragma unroll
        for (int o = 32; o; o >>= 1) m = fmaxf(m, __shfl_down(m, o));
        if (tid == 0) red2[0] = m;
    }
    __syncthreads();
    float mx = red2[0];
    if (tid < 128) sc[tid] = __expf(sc[tid] - mx);
    __syncthreads();
    if (tid < 64) {
        float sm = sc[tid] + sc[tid + 64];
#pragma unroll
        for (int o = 32; o; o >>= 1) sm += __shfl_down(sm, o);
        if (tid == 0) red2[1] = sm;
    }
    __syncthreads();
    float inv = 1.f / red2[1];
    if (tid < 128) {
        sc[tid] *= inv;
        a_mat[bt * 128 + tid] = sc[tid];
    }
    __syncthreads();

    float c0 = 0.f, c1 = 0.f, c2 = 0.f;
    for (int s2 = 0; s2 < 128; ++s2) {
        float as = sc[s2];
        const float* hrow = &hs[((long)(b * Tt + s2)) * Hh];
        c0 = fmaf(as, hrow[tid], c0);
        c1 = fmaf(as, hrow[tid + 256], c1);
        c2 = fmaf(as, hrow[tid + 512], c2);
    }
    crow[tid] = c0; crow[tid + 256] = c1; crow[tid + 512] = c2;
    __syncthreads();

    for (int l = 0; l < Ll; ++l) {
        float p = 0.f;
        for (int h = tid; h < 2 * Hh; h += 256) {
            float u = (h < Hh) ? hsr[h] : crow[h - Hh];
            p = fmaf(u, Wclf[l * 2 * Hh + h], p);
        }
#pragma unroll
        for (int o = 32; o; o >>= 1) p += __shfl_down(p, o);
        if ((tid & 63) == 0) tmp[tid >> 6] = p;
        __syncthreads();
        if (tid == 0) logits[bt * Ll + l] = tmp[0] + tmp[1] + tmp[2] + tmp[3];
        __syncthreads();
    }
}

// ---------------------------------------------------------------------------
// a_t normalization (unchanged)
// ---------------------------------------------------------------------------
__global__ void k_norm(const float* __restrict__ a_mat, float* __restrict__ a_t)
{
    int b = blockIdx.x;
    int s = threadIdx.x;
    float sum = 0.f;
    for (int t = 0; t < Tt; ++t) sum += a_mat[((long)(b * Tt + t)) * 128 + s];
    __shared__ float pool[128];
    __shared__ float tot;
    pool[s] = sum;
    __syncthreads();
    if (s < 64) {
        float v2 = pool[s] + pool[s + 64];
#pragma unroll
        for (int o = 32; o; o >>= 1) v2 += __shfl_down(v2, o);
        if (s == 0) tot = v2;
    }
    __syncthreads();
    float tv = tot;
    a_t[b * 128 + s] = (tv != 0.f) ? pool[s] / tv : 0.f;
}

// ---------------------------------------------------------------------------
// Viterbi (unchanged)
// ---------------------------------------------------------------------------
__global__ void k_viterbi(const float* __restrict__ logits, const float* __restrict__ trans,
                          const float* __restrict__ start, const float* __restrict__ endw,
                          float* __restrict__ out)
{
    __shared__ float sc[2][72];
    __shared__ unsigned char ptrs[127][72];
    __shared__ unsigned char tags[8][128];
    int tid = threadIdx.x;
    int b = tid / 9, j = tid % 9;
    bool act = tid < 72;
    if (act) sc[0][b * 9 + j] = start[j] + logits[(b * Tt + 0) * Ll + j];
    __syncthreads();
    for (int t = 1; t < Tt; ++t) {
        int cur = t & 1, prv = cur ^ 1;
        if (act) {
            float best = -1e30f; int bi = 0;
#pragma unroll
            for (int i = 0; i < 9; ++i) {
                float vv = sc[prv][b * 9 + i] + trans[i * 9 + j];
                if (vv > best) { best = vv; bi = i; }
            }
            sc[cur][b * 9 + j] = best + logits[(b * Tt + t) * Ll + j];
            ptrs[t - 1][b * 9 + j] = (unsigned char)bi;
        }
        __syncthreads();
    }
    if (act && j == 0) {
        float best = -1e30f; int bj = 0;
#pragma unroll
        for (int jj = 0; jj < 9; ++jj) {
            float vv = sc[1][b * 9 + jj] + endw[jj];
            if (vv > best) { best = vv; bj = jj; }
        }
        int tg = bj;
        tags[b][127] = (unsigned char)tg;
        for (int t = 127; t >= 1; --t) {
            tg = ptrs[t - 1][b * 9 + tg];
            tags[b][t - 1] = (unsigned char)tg;
        }
    }
    __syncthreads();
    for (int i = tid; i < Bq * Tt * Ll; i += blockDim.x) {
        int l = i % 9;
        int btx = i / 9;
        int tt2 = btx % Tt;
        int bb = btx / Tt;
        out[i] = (tags[bb][tt2] == l) ? 10.f : -1.f;
    }
}

// ---------------------------------------------------------------------------
extern "C" void kernel_launch(void* const* d_in, const int* in_sizes, int n_in,
                              void* d_out, int out_size, void* d_ws, size_t ws_size,
                              hipStream_t stream)
{
    const float* embeds   = (const float*)d_in[0];
    const int*   qids     = (const int*)d_in[1];
    const float* w_ih_l0  = (const float*)d_in[2];
    const float* w_ih_rest= (const float*)d_in[3];
    const float* w_hh     = (const float*)d_in[4];
    const float* b_ih     = (const float*)d_in[5];
    const float* b_hh     = (const float*)d_in[6];
    const float* W_H      = (const float*)d_in[7];
    const float* W_p      = (const float*)d_in[8];
    const float* W_h      = (const float*)d_in[9];
    const float* vvec     = (const float*)d_in[10];
    const float* W_clf    = (const float*)d_in[11];
    const float* trans    = (const float*)d_in[12];
    const float* cstart   = (const float*)d_in[13];
    const float* cend     = (const float*)d_in[14];

    float* out = (float*)d_out;
    float* vit_out = out;                          // 8*128*9   = 9216
    float* hs      = out + 9216;                   // 8*128*768 = 786432
    float* a_t     = out + 9216 + 786432;          // 8*128     = 1024

    float* ws = (float*)d_ws;
    float* G      = ws;                  // 3145728 floats
    float* Y0     = ws + 3145728;        // 786432
    float* Y1     = Y0 + 786432;         // 786432 (contiguous with Y0)
    float* A1     = ws;                  // reuses G (dead after last lstm)
    float* A2     = A1 + 786432;
    float* pterm  = A2 + 786432;
    float* a_mat  = pterm + 6144;
    float* logits = a_mat + 131072;

    dim3 blk(256);
    const int nY4 = 2 * 786432 / 4;      // Y0+Y1 float4 count
    const int nH4 = 786432 / 4;          // hs float4 count
    const int fillgrid = (nY4 + nH4 + 255) / 256;

    // Sentinel pre-fill of the three exchange buffers (one launch).
    k_fill_sent2<<<dim3(fillgrid), blk, 0, stream>>>(Y0, nY4, hs, nH4);

    // ---- Layer 0 ----
    k_gemm<<<dim3(GATE / BN, 1024 / BM, 2), blk, 0, stream>>>(
        embeds, w_ih_l0, G, 1024, GATE, Ee,
        0L, (long)GATE * Ee, (long)1024 * GATE,
        b_ih, b_hh, (long)GATE, nullptr);
    k_lstm<<<dim3(128), blk, 0, stream>>>(G, w_hh, Y0);

    // ---- Layer 1 ----
    k_gemm<<<dim3(GATE / BN, 1024 / BM, 2), blk, 0, stream>>>(
        Y0, w_ih_rest, G, 1024, GATE, Hh,
        0L, (long)GATE * Hh, (long)1024 * GATE,
        b_ih + 2 * GATE, b_hh + 2 * GATE, (long)GATE, nullptr);
    k_lstm<<<dim3(128), blk, 0, stream>>>(G, w_hh + (long)2 * GATE * Ee, Y1);

    // ---- Layer 2 ----
    k_gemm<<<dim3(GATE / BN, 1024 / BM, 2), blk, 0, stream>>>(
        Y1, w_ih_rest + (long)2 * GATE * Hh, G, 1024, GATE, Hh,
        0L, (long)GATE * Hh, (long)1024 * GATE,
        b_ih + 4 * GATE, b_hh + 4 * GATE, (long)GATE, nullptr);
    k_lstm<<<dim3(128), blk, 0, stream>>>(G, w_hh + (long)4 * GATE * Ee, hs);

    // ---- Attention precompute ----
    k_pterm<<<dim3(24, 8), blk, 0, stream>>>(hs, qids, W_p, pterm);
    k_gemm<<<dim3(Hh / BN, 1024 / BM, 1), blk, 0, stream>>>(
        hs, W_H, A1, 1024, Hh, Hh, 0L, 0L, 0L, nullptr, nullptr, 0L, nullptr);
    k_gemm<<<dim3(Hh / BN, 1024 / BM, 1), blk, 0, stream>>>(
        hs, W_h, A2, 1024, Hh, Hh, 0L, 0L, 0L, nullptr, nullptr, 0L, pterm);

    // ---- Fused attention + logits ----
    k_attn<<<dim3(1024), blk, 0, stream>>>(hs, A1, A2, vvec, W_clf, a_mat, logits);

    // ---- Pooled attention norm -> a_t ----
    k_norm<<<dim3(8), dim3(128), 0, stream>>>(a_mat, a_t);

    // ---- Viterbi -> vit_logits ----
    k_viterbi<<<dim3(1), dim3(128), 0, stream>>>(logits, trans, cstart, cend, vit_out);
}

// Round 14
// 1908.607 us; speedup vs baseline: 1.1454x; 1.1454x over previous
//
#include <hip/hip_runtime.h>
#include <math.h>

// Problem constants
#define Bq 8
#define Tt 128
#define Ee 384
#define Hh 768
#define Ll 9
#define GATE 1536   // 4*E

__device__ __forceinline__ float fast_sigmoid(float x) {
    return 1.f / (1.f + __expf(-x));
}
__device__ __forceinline__ float fast_tanh(float x) {
    return 1.f - 2.f / (__expf(2.f * x) + 1.f);
}

// ---------------------------------------------------------------------------
// Generic f32 GEMM, 64x64 tiles (R12 known-good).
// C[m,n] = sum_k A[m,k]*Bw[n,k] + b1[n] + b2[n] + bbn[m>>7][n]
// ---------------------------------------------------------------------------
#define BM 64
#define BN 64
#define BKk 16

__global__ __launch_bounds__(256) void k_gemm(
    const float* __restrict__ A, const float* __restrict__ Bw, float* __restrict__ C,
    int M, int N, int K,
    long sAz, long sBz, long sCz,
    const float* __restrict__ b1, const float* __restrict__ b2, long sbz,
    const float* __restrict__ bbn)
{
    int z = blockIdx.z;
    A += (long)z * sAz;
    Bw += (long)z * sBz;
    C += (long)z * sCz;
    const float* bb1 = b1 ? b1 + (long)z * sbz : nullptr;
    const float* bb2 = b2 ? b2 + (long)z * sbz : nullptr;

    int n0 = blockIdx.x * BN;
    int m0 = blockIdx.y * BM;
    int tid = threadIdx.x;

    __shared__ float As[BKk][BM];
    __shared__ float Bs[BKk][BN];

    int lr = tid & 63;          // row within tile
    int lc = (tid >> 6) * 4;    // col group 0,4,8,12
    int tx = tid & 15;          // microtile col
    int ty = tid >> 4;          // microtile row

    float acc[4][4];
#pragma unroll
    for (int i = 0; i < 4; ++i)
#pragma unroll
        for (int j = 0; j < 4; ++j) acc[i][j] = 0.f;

    for (int k0 = 0; k0 < K; k0 += BKk) {
        float4 a0 = *(const float4*)&A[(long)(m0 + lr) * K + k0 + lc];
        float4 w0 = *(const float4*)&Bw[(long)(n0 + lr) * K + k0 + lc];
        __syncthreads();
        As[lc + 0][lr] = a0.x; As[lc + 1][lr] = a0.y; As[lc + 2][lr] = a0.z; As[lc + 3][lr] = a0.w;
        Bs[lc + 0][lr] = w0.x; Bs[lc + 1][lr] = w0.y; Bs[lc + 2][lr] = w0.z; Bs[lc + 3][lr] = w0.w;
        __syncthreads();
#pragma unroll
        for (int kk = 0; kk < BKk; ++kk) {
            float av[4], bv[4];
            *(float4*)&av[0] = *(float4*)&As[kk][ty * 4];
            *(float4*)&bv[0] = *(float4*)&Bs[kk][tx * 4];
#pragma unroll
            for (int i = 0; i < 4; ++i)
#pragma unroll
                for (int j = 0; j < 4; ++j)
                    acc[i][j] = fmaf(av[i], bv[j], acc[i][j]);
        }
    }

#pragma unroll
    for (int i = 0; i < 4; ++i) {
        long m = m0 + ty * 4 + i;
#pragma unroll
        for (int j = 0; j < 4; ++j) {
            int n = n0 + tx * 4 + j;
            float val = acc[i][j];
            if (bb1) val += bb1[n];
            if (bb2) val += bb2[n];
            if (bbn) val += bbn[(m >> 7) * (long)N + n];
            C[m * N + n] = val;
        }
    }
}

// ---------------------------------------------------------------------------
// Combined attention GEMM: z=0 -> C0 = hs@W0.T ; z=1 -> C1 = hs@W1.T + bbn.
// Runs both 192-block GEMMs concurrently (384 blocks total).
// ---------------------------------------------------------------------------
__global__ __launch_bounds__(256) void k_gemm2(
    const float* __restrict__ A,
    const float* __restrict__ W0, const float* __restrict__ W1,
    float* __restrict__ C0, float* __restrict__ C1,
    int M, int N, int K,
    const float* __restrict__ bbn)
{
    int z = blockIdx.z;
    const float* Bw = z ? W1 : W0;
    float* C = z ? C1 : C0;
    const float* bb = z ? bbn : nullptr;

    int n0 = blockIdx.x * BN;
    int m0 = blockIdx.y * BM;
    int tid = threadIdx.x;

    __shared__ float As[BKk][BM];
    __shared__ float Bs[BKk][BN];

    int lr = tid & 63;
    int lc = (tid >> 6) * 4;
    int tx = tid & 15;
    int ty = tid >> 4;

    float acc[4][4];
#pragma unroll
    for (int i = 0; i < 4; ++i)
#pragma unroll
        for (int j = 0; j < 4; ++j) acc[i][j] = 0.f;

    for (int k0 = 0; k0 < K; k0 += BKk) {
        float4 a0 = *(const float4*)&A[(long)(m0 + lr) * K + k0 + lc];
        float4 w0 = *(const float4*)&Bw[(long)(n0 + lr) * K + k0 + lc];
        __syncthreads();
        As[lc + 0][lr] = a0.x; As[lc + 1][lr] = a0.y; As[lc + 2][lr] = a0.z; As[lc + 3][lr] = a0.w;
        Bs[lc + 0][lr] = w0.x; Bs[lc + 1][lr] = w0.y; Bs[lc + 2][lr] = w0.z; Bs[lc + 3][lr] = w0.w;
        __syncthreads();
#pragma unroll
        for (int kk = 0; kk < BKk; ++kk) {
            float av[4], bv[4];
            *(float4*)&av[0] = *(float4*)&As[kk][ty * 4];
            *(float4*)&bv[0] = *(float4*)&Bs[kk][tx * 4];
#pragma unroll
            for (int i = 0; i < 4; ++i)
#pragma unroll
                for (int j = 0; j < 4; ++j)
                    acc[i][j] = fmaf(av[i], bv[j], acc[i][j]);
        }
    }

#pragma unroll
    for (int i = 0; i < 4; ++i) {
        long m = m0 + ty * 4 + i;
#pragma unroll
        for (int j = 0; j < 4; ++j) {
            int n = n0 + tx * 4 + j;
            float val = acc[i][j];
            if (bb) val += bb[(m >> 7) * (long)N + n];
            C[m * N + n] = val;
        }
    }
}

// ---------------------------------------------------------------------------
// LSTM recurrence, sentinel-dataflow with SWEEP polling (R12-exact, 497 us).
// 64 blocks: d = bid>>5, slice s = bid&31 owns h-rows s*12..s*12+11.
// W 72 floats/thread register-resident (VGPR=104, no spill).
// Yout pre-filled with 0xFFFFFFFF (NaN); h always finite.
// ---------------------------------------------------------------------------
__device__ __forceinline__ bool has_sent(unsigned long long v) {
    return ((unsigned)v == 0xFFFFFFFFu) || ((unsigned)(v >> 32) == 0xFFFFFFFFu);
}

__global__ __launch_bounds__(256, 1) void k_lstm(
    const float* __restrict__ G, const float* __restrict__ Whh, float* Yout)
{
    int bid = blockIdx.x;
    int d = bid >> 5;           // direction
    int s = bid & 31;           // slice: h-rows s*12..s*12+11
    int tid = threadIdx.x;
    int kq = tid >> 4;          // 0..15 (k-range of 24)
    int rg = tid & 15;          // 0..15 (3 gate-rows each)
    int kq24 = kq * 24;

    __shared__ float hl[8 * 384];       // h_prev for all batches of this dir
    __shared__ float part[16 * 392];    // [kq][b(stride 49)][rl 0..47]

    // W slice: 3 gate rows x 24 k = 72 floats (register-resident)
    float W_[3][24];
    const float* Wd = Whh + (long)d * GATE * Ee;
#pragma unroll
    for (int r = 0; r < 3; ++r) {
        int rl = rg * 3 + r;            // 0..47
        int g = rl / 12, rr = rl % 12;
        const float* src = Wd + (long)(g * Ee + s * 12 + rr) * Ee + kq24;
#pragma unroll
        for (int k4 = 0; k4 < 6; ++k4) {
            float4 w = *(const float4*)&src[k4 * 4];
            W_[r][k4 * 4 + 0] = w.x;
            W_[r][k4 * 4 + 1] = w.y;
            W_[r][k4 * 4 + 2] = w.z;
            W_[r][k4 * 4 + 3] = w.w;
        }
    }

    float cst = 0.f;                    // cell state for update thread
    bool upd = tid < 96;
    int ub = upd ? (tid / 12) : 0;      // batch
    int ur = upd ? (tid - ub * 12) : 0; // h-row within slice

    // G prefetch (one timestep ahead)
    float gpre[4];
    const float* gbase = G + ((long)d * 1024 + ub * Tt) * GATE + s * 12 + ur;
    {
        int tt0 = d ? 127 : 0;
        if (upd) {
#pragma unroll
            for (int g = 0; g < 4; ++g) gpre[g] = gbase[(long)tt0 * GATE + g * Ee];
        }
    }

    float4* hl4 = (float4*)hl;

    for (int it = 0; it < 128; ++it) {
        int tt = d ? (127 - it) : it;
        int tp = d ? (tt + 1) : (tt - 1);

        // stage h_{prev}: parallel-issue all 6 words, sweep-verify
        if (it == 0) {
            float4 z4 = make_float4(0.f, 0.f, 0.f, 0.f);
#pragma unroll
            for (int ii = 0; ii < 3; ++ii) hl4[tid + 256 * ii] = z4;
        } else {
            const unsigned long long* sp[6];
            unsigned long long v[6];
#pragma unroll
            for (int ii = 0; ii < 3; ++ii) {
                int i4 = tid + 256 * ii;       // 0..767
                int b = i4 / 96, k4 = i4 - b * 96;
                const unsigned long long* base = (const unsigned long long*)
                    &Yout[((long)(b * Tt + tp)) * Hh + d * Ee + k4 * 4];
                sp[2 * ii] = base;
                sp[2 * ii + 1] = base + 1;
            }
#pragma unroll
            for (int j = 0; j < 6; ++j)
                v[j] = __hip_atomic_load(sp[j], __ATOMIC_RELAXED, __HIP_MEMORY_SCOPE_AGENT);
            for (;;) {
                bool any = false;
#pragma unroll
                for (int j = 0; j < 6; ++j) {
                    if (has_sent(v[j])) {
                        v[j] = __hip_atomic_load(sp[j], __ATOMIC_RELAXED, __HIP_MEMORY_SCOPE_AGENT);
                        any = true;
                    }
                }
                if (!any) break;
            }
#pragma unroll
            for (int ii = 0; ii < 3; ++ii) {
                int i4 = tid + 256 * ii;
                float2 flo = __builtin_bit_cast(float2, v[2 * ii]);
                float2 fhi = __builtin_bit_cast(float2, v[2 * ii + 1]);
                hl4[i4] = make_float4(flo.x, flo.y, fhi.x, fhi.y);
            }
        }
        __syncthreads();

        float acc[8][3];
#pragma unroll
        for (int b = 0; b < 8; ++b)
#pragma unroll
            for (int r = 0; r < 3; ++r) acc[b][r] = 0.f;

#pragma unroll
        for (int k4 = 0; k4 < 6; ++k4) {
#pragma unroll
            for (int b = 0; b < 8; ++b) {
                float4 hv = *(const float4*)&hl[b * 384 + kq24 + k4 * 4];
#pragma unroll
                for (int r = 0; r < 3; ++r) {
                    acc[b][r] = fmaf(W_[r][k4 * 4 + 0], hv.x, acc[b][r]);
                    acc[b][r] = fmaf(W_[r][k4 * 4 + 1], hv.y, acc[b][r]);
                    acc[b][r] = fmaf(W_[r][k4 * 4 + 2], hv.z, acc[b][r]);
                    acc[b][r] = fmaf(W_[r][k4 * 4 + 3], hv.w, acc[b][r]);
                }
            }
        }

        // write partials
#pragma unroll
        for (int b = 0; b < 8; ++b)
#pragma unroll
            for (int r = 0; r < 3; ++r)
                part[kq * 392 + b * 49 + rg * 3 + r] = acc[b][r];
        __syncthreads();

        if (upd) {
            float gt[4];
#pragma unroll
            for (int g = 0; g < 4; ++g) {
                int rl = g * 12 + ur;
                float sum = gpre[g];
#pragma unroll
                for (int q = 0; q < 16; ++q) sum += part[q * 392 + ub * 49 + rl];
                gt[g] = sum;
            }
            float ig = fast_sigmoid(gt[0]);
            float fg = fast_sigmoid(gt[1]);
            float gg = fast_tanh(gt[2]);
            float og = fast_sigmoid(gt[3]);
            cst = fg * cst + ig * gg;
            float h = og * fast_tanh(cst);
            // fire-and-forget write-through store to the coherence point
            __hip_atomic_store(&Yout[((long)(ub * Tt + tt)) * Hh + d * Ee + s * 12 + ur],
                               h, __ATOMIC_RELAXED, __HIP_MEMORY_SCOPE_AGENT);
            // prefetch next step's G (overlaps next staging)
            if (it != 127) {
                int ttn = d ? (tt - 1) : (tt + 1);
#pragma unroll
                for (int g = 0; g < 4; ++g) gpre[g] = gbase[(long)ttn * GATE + g * Ee];
            }
        }
    }
}

// ---------------------------------------------------------------------------
// Sentinel pre-fill (one launch for Y0+Y1 contiguous region and hs)
// ---------------------------------------------------------------------------
__global__ void k_fill_sent2(float* __restrict__ a, int na4,
                             float* __restrict__ b, int nb4)
{
    int i = blockIdx.x * 256 + threadIdx.x;
    unsigned u = 0xFFFFFFFFu;
    float f = __builtin_bit_cast(float, u);
    float4 f4 = make_float4(f, f, f, f);
    if (i < na4) ((float4*)a)[i] = f4;
    else {
        int j = i - na4;
        if (j < nb4) ((float4*)b)[j] = f4;
    }
}

// ---------------------------------------------------------------------------
// p_term (unchanged)
// ---------------------------------------------------------------------------
__global__ __launch_bounds__(256) void k_pterm(
    const float* __restrict__ hs, const int* __restrict__ qids,
    const float* __restrict__ Wp, float* __restrict__ pterm)
{
    int b = blockIdx.y;
    int chunk = blockIdx.x;
    int tid = threadIdx.x;
    int qid = qids[b];
    __shared__ float hp[Hh];
    for (int i = tid; i < Hh; i += 256) hp[i] = hs[((long)(b * Tt + qid)) * Hh + i];
    __syncthreads();
    int w = tid >> 6, lane = tid & 63;
#pragma unroll
    for (int r = 0; r < 8; ++r) {
        int n = chunk * 32 + w * 8 + r;
        const float* wrow = &Wp[(long)n * Hh];
        float p = 0.f;
#pragma unroll
        for (int k0 = 0; k0 < 3; ++k0) {
            int k = lane * 4 + k0 * 256;
            float4 wv = *(const float4*)&wrow[k];
            float4 hv = *(const float4*)&hp[k];
            p += wv.x * hv.x + wv.y * hv.y + wv.z * hv.z + wv.w * hv.w;
        }
#pragma unroll
        for (int o = 32; o; o >>= 1) p += __shfl_down(p, o);
        if (lane == 0) pterm[b * Hh + n] = p;
    }
}

// ---------------------------------------------------------------------------
// Fused attention (unchanged)
// ---------------------------------------------------------------------------
__global__ __launch_bounds__(256) void k_attn(
    const float* __restrict__ hs, const float* __restrict__ A1, const float* __restrict__ A2,
    const float* __restrict__ v, const float* __restrict__ Wclf,
    float* __restrict__ a_mat, float* __restrict__ logits)
{
    int b = blockIdx.x >> 7, t = blockIdx.x & 127;
    int tid = threadIdx.x;
    long bt = (long)(b * Tt + t);

    __shared__ float a2r[Hh], vr[Hh], hsr[Hh], crow[Hh];
    __shared__ float sc[128], tmp[256], red2[2];

    for (int i = tid; i < Hh; i += 256) {
        a2r[i] = A2[bt * Hh + i];
        vr[i] = v[i];
        hsr[i] = hs[bt * Hh + i];
    }
    __syncthreads();

    {
        int sid = tid >> 1, half = tid & 1;
        float p = 0.f;
        const float* A1r = &A1[((long)(b * Tt + sid)) * Hh + half * 384];
        const float* a2h = &a2r[half * 384];
        const float* vh = &vr[half * 384];
        for (int k = 0; k < 384; k += 4) {
            float4 z = *(const float4*)&A1r[k];
            p += vh[k + 0] * fast_tanh(z.x + a2h[k + 0]);
            p += vh[k + 1] * fast_tanh(z.y + a2h[k + 1]);
            p += vh[k + 2] * fast_tanh(z.z + a2h[k + 2]);
            p += vh[k + 3] * fast_tanh(z.w + a2h[k + 3]);
        }
        tmp[tid] = p;
    }
    __syncthreads();
    if (tid < 128) sc[tid] = tmp[2 * tid] + tmp[2 * tid + 1];
    __syncthreads();

    if (tid < 64) {
        float m = fmaxf(sc[tid], sc[tid + 64]);
#pragma unroll
        for (int o = 32; o; o >>= 1) m = fmaxf(m, __shfl_down(m, o));
        if (tid == 0) red2[0] = m;
    }
    __syncthreads();
    float mx = red2[0];
    if (tid < 128) sc[tid] = __expf(sc[tid] - mx);
    __syncthreads();
    if (tid < 64) {
        float sm = sc[tid] + sc[tid + 64];
#pragma unroll
        for (int o = 32; o; o >>= 1) sm += __shfl_down(sm, o);
        if (tid == 0) red2[1] = sm;
    }
    __syncthreads();
    float inv = 1.f / red2[1];
    if (tid < 128) {
        sc[tid] *= inv;
        a_mat[bt * 128 + tid] = sc[tid];
    }
    __syncthreads();

    float c0 = 0.f, c1 = 0.f, c2 = 0.f;
    for (int s2 = 0; s2 < 128; ++s2) {
        float as = sc[s2];
        const float* hrow = &hs[((long)(b * Tt + s2)) * Hh];
        c0 = fmaf(as, hrow[tid], c0);
        c1 = fmaf(as, hrow[tid + 256], c1);
        c2 = fmaf(as, hrow[tid + 512], c2);
    }
    crow[tid] = c0; crow[tid + 256] = c1; crow[tid + 512] = c2;
    __syncthreads();

    for (int l = 0; l < Ll; ++l) {
        float p = 0.f;
        for (int h = tid; h < 2 * Hh; h += 256) {
            float u = (h < Hh) ? hsr[h] : crow[h - Hh];
            p = fmaf(u, Wclf[l * 2 * Hh + h], p);
        }
#pragma unroll
        for (int o = 32; o; o >>= 1) p += __shfl_down(p, o);
        if ((tid & 63) == 0) tmp[tid >> 6] = p;
        __syncthreads();
        if (tid == 0) logits[bt * Ll + l] = tmp[0] + tmp[1] + tmp[2] + tmp[3];
        __syncthreads();
    }
}

// ---------------------------------------------------------------------------
// a_t normalization (unchanged)
// ---------------------------------------------------------------------------
__global__ void k_norm(const float* __restrict__ a_mat, float* __restrict__ a_t)
{
    int b = blockIdx.x;
    int s = threadIdx.x;
    float sum = 0.f;
    for (int t = 0; t < Tt; ++t) sum += a_mat[((long)(b * Tt + t)) * 128 + s];
    __shared__ float pool[128];
    __shared__ float tot;
    pool[s] = sum;
    __syncthreads();
    if (s < 64) {
        float v2 = pool[s] + pool[s + 64];
#pragma unroll
        for (int o = 32; o; o >>= 1) v2 += __shfl_down(v2, o);
        if (s == 0) tot = v2;
    }
    __syncthreads();
    float tv = tot;
    a_t[b * 128 + s] = (tv != 0.f) ? pool[s] / tv : 0.f;
}

// ---------------------------------------------------------------------------
// Viterbi (unchanged)
// ---------------------------------------------------------------------------
__global__ void k_viterbi(const float* __restrict__ logits, const float* __restrict__ trans,
                          const float* __restrict__ start, const float* __restrict__ endw,
                          float* __restrict__ out)
{
    __shared__ float sc[2][72];
    __shared__ unsigned char ptrs[127][72];
    __shared__ unsigned char tags[8][128];
    int tid = threadIdx.x;
    int b = tid / 9, j = tid % 9;
    bool act = tid < 72;
    if (act) sc[0][b * 9 + j] = start[j] + logits[(b * Tt + 0) * Ll + j];
    __syncthreads();
    for (int t = 1; t < Tt; ++t) {
        int cur = t & 1, prv = cur ^ 1;
        if (act) {
            float best = -1e30f; int bi = 0;
#pragma unroll
            for (int i = 0; i < 9; ++i) {
                float vv = sc[prv][b * 9 + i] + trans[i * 9 + j];
                if (vv > best) { best = vv; bi = i; }
            }
            sc[cur][b * 9 + j] = best + logits[(b * Tt + t) * Ll + j];
            ptrs[t - 1][b * 9 + j] = (unsigned char)bi;
        }
        __syncthreads();
    }
    if (act && j == 0) {
        float best = -1e30f; int bj = 0;
#pragma unroll
        for (int jj = 0; jj < 9; ++jj) {
            float vv = sc[1][b * 9 + jj] + endw[jj];
            if (vv > best) { best = vv; bj = jj; }
        }
        int tg = bj;
        tags[b][127] = (unsigned char)tg;
        for (int t = 127; t >= 1; --t) {
            tg = ptrs[t - 1][b * 9 + tg];
            tags[b][t - 1] = (unsigned char)tg;
        }
    }
    __syncthreads();
    for (int i = tid; i < Bq * Tt * Ll; i += blockDim.x) {
        int l = i % 9;
        int btx = i / 9;
        int tt2 = btx % Tt;
        int bb = btx / Tt;
        out[i] = (tags[bb][tt2] == l) ? 10.f : -1.f;
    }
}

// ---------------------------------------------------------------------------
extern "C" void kernel_launch(void* const* d_in, const int* in_sizes, int n_in,
                              void* d_out, int out_size, void* d_ws, size_t ws_size,
                              hipStream_t stream)
{
    const float* embeds   = (const float*)d_in[0];
    const int*   qids     = (const int*)d_in[1];
    const float* w_ih_l0  = (const float*)d_in[2];
    const float* w_ih_rest= (const float*)d_in[3];
    const float* w_hh     = (const float*)d_in[4];
    const float* b_ih     = (const float*)d_in[5];
    const float* b_hh     = (const float*)d_in[6];
    const float* W_H      = (const float*)d_in[7];
    const float* W_p      = (const float*)d_in[8];
    const float* W_h      = (const float*)d_in[9];
    const float* vvec     = (const float*)d_in[10];
    const float* W_clf    = (const float*)d_in[11];
    const float* trans    = (const float*)d_in[12];
    const float* cstart   = (const float*)d_in[13];
    const float* cend     = (const float*)d_in[14];

    float* out = (float*)d_out;
    float* vit_out = out;                          // 8*128*9   = 9216
    float* hs      = out + 9216;                   // 8*128*768 = 786432
    float* a_t     = out + 9216 + 786432;          // 8*128     = 1024

    float* ws = (float*)d_ws;
    float* G      = ws;                  // 3145728 floats
    float* Y0     = ws + 3145728;        // 786432
    float* Y1     = Y0 + 786432;         // 786432 (contiguous with Y0)
    float* A1     = ws;                  // reuses G (dead after last lstm)
    float* A2     = A1 + 786432;
    float* pterm  = A2 + 786432;
    float* a_mat  = pterm + 6144;
    float* logits = a_mat + 131072;

    dim3 blk(256);
    const int nY4 = 2 * 786432 / 4;      // Y0+Y1 float4 count
    const int nH4 = 786432 / 4;          // hs float4 count
    const int fillgrid = (nY4 + nH4 + 255) / 256;

    // Sentinel pre-fill of the three exchange buffers (one launch).
    k_fill_sent2<<<dim3(fillgrid), blk, 0, stream>>>(Y0, nY4, hs, nH4);

    // ---- Layer 0 ----
    k_gemm<<<dim3(GATE / BN, 1024 / BM, 2), blk, 0, stream>>>(
        embeds, w_ih_l0, G, 1024, GATE, Ee,
        0L, (long)GATE * Ee, (long)1024 * GATE,
        b_ih, b_hh, (long)GATE, nullptr);
    k_lstm<<<dim3(64), blk, 0, stream>>>(G, w_hh, Y0);

    // ---- Layer 1 ----
    k_gemm<<<dim3(GATE / BN, 1024 / BM, 2), blk, 0, stream>>>(
        Y0, w_ih_rest, G, 1024, GATE, Hh,
        0L, (long)GATE * Hh, (long)1024 * GATE,
        b_ih + 2 * GATE, b_hh + 2 * GATE, (long)GATE, nullptr);
    k_lstm<<<dim3(64), blk, 0, stream>>>(G, w_hh + (long)2 * GATE * Ee, Y1);

    // ---- Layer 2 ----
    k_gemm<<<dim3(GATE / BN, 1024 / BM, 2), blk, 0, stream>>>(
        Y1, w_ih_rest + (long)2 * GATE * Hh, G, 1024, GATE, Hh,
        0L, (long)GATE * Hh, (long)1024 * GATE,
        b_ih + 4 * GATE, b_hh + 4 * GATE, (long)GATE, nullptr);
    k_lstm<<<dim3(64), blk, 0, stream>>>(G, w_hh + (long)4 * GATE * Ee, hs);

    // ---- Attention precompute: pterm, then A1+A2 fused (concurrent) ----
    k_pterm<<<dim3(24, 8), blk, 0, stream>>>(hs, qids, W_p, pterm);
    k_gemm2<<<dim3(Hh / BN, 1024 / BM, 2), blk, 0, stream>>>(
        hs, W_H, W_h, A1, A2, 1024, Hh, Hh, pterm);

    // ---- Fused attention + logits ----
    k_attn<<<dim3(1024), blk, 0, stream>>>(hs, A1, A2, vvec, W_clf, a_mat, logits);

    // ---- Pooled attention norm -> a_t ----
    k_norm<<<dim3(8), dim3(128), 0, stream>>>(a_mat, a_t);

    // ---- Viterbi -> vit_logits ----
    k_viterbi<<<dim3(1), dim3(128), 0, stream>>>(logits, trans, cstart, cend, vit_out);
}